// Round 2
// baseline (12412.634 us; speedup 1.0000x reference)
//
#include <hip/hip_runtime.h>

#define NB 8
#define TT 24
#define NN 4000
#define FF 32
#define HH 128
#define EE 64000

__device__ __forceinline__ float fsig(float x) { return 1.0f / (1.0f + __expf(-x)); }
__device__ __forceinline__ float ftanh(float x) { float e = __expf(2.0f * x); return 1.0f - 2.0f / (e + 1.0f); }

// ---------- setup: pack weights, combine bias, init deg ----------
// Wq_hh flat idx = ((k4*8 + gi)*64 + jp)*4 + q  -> W_hh[(g*128 + 2*jp + jj)*128 + k4*4 + q]
// Wq_ih flat idx = ((f4*8 + gi)*64 + jp)*4 + q  -> W_ih[(g*128 + 2*jp + jj)*32  + f4*4 + q]
//   where gi = g*2 + jj
__global__ void setup_kernel(const float* __restrict__ W_ih, const float* __restrict__ W_hh,
                             const float* __restrict__ b_ih, const float* __restrict__ b_hh,
                             const float* __restrict__ gcn_W,
                             float* __restrict__ Wq_hh, float* __restrict__ Wq_ih,
                             float* __restrict__ gcn_WT, float* __restrict__ bias,
                             float* __restrict__ deg) {
  int idx = blockIdx.x * 256 + threadIdx.x;
  if (idx < 65536) {
    int q = idx & 3, jp = (idx >> 2) & 63, gi = (idx >> 8) & 7, k4 = idx >> 11;
    int g = gi >> 1, jj = gi & 1;
    Wq_hh[idx] = W_hh[(g * 128 + 2 * jp + jj) * 128 + k4 * 4 + q];
  } else if (idx < 65536 + 16384) {
    int i2 = idx - 65536;
    int q = i2 & 3, jp = (i2 >> 2) & 63, gi = (i2 >> 8) & 7, f4 = i2 >> 11;
    int g = gi >> 1, jj = gi & 1;
    Wq_ih[i2] = W_ih[(g * 128 + 2 * jp + jj) * 32 + f4 * 4 + q];
  } else if (idx < 65536 + 16384 + 16384) {
    int i2 = idx - 65536 - 16384;
    int g = i2 & 127, k = i2 >> 7;
    gcn_WT[i2] = gcn_W[g * 128 + k];
  } else if (idx < 65536 + 16384 + 16384 + 512) {
    int g = idx - (65536 + 16384 + 16384);
    bias[g] = b_ih[g] + b_hh[g];
  } else if (idx < 65536 + 16384 + 16384 + 512 + NN) {
    int n = idx - (65536 + 16384 + 16384 + 512);
    deg[n] = 1.0f;  // self-loop
  }
}

// ---------- LSTM: 1 wave per block, 8 sequences, lane owns 8 gate-cols (4g x 2j) ----------
__global__ __launch_bounds__(64, 3) void lstm_kernel(
    const float* __restrict__ x,       // [B,T,N,F]
    const float* __restrict__ Wq_ih,   // packed
    const float* __restrict__ Wq_hh,   // packed
    const float* __restrict__ bias,    // [512] combined
    float* __restrict__ h_out)         // [B*N, H]
{
  __shared__ float h_lds[8 * HH];
  __shared__ float x_lds[8 * FF];
  const int jp = threadIdx.x;
  const int blk = blockIdx.x;
  const int b = blk / (NN / 8);
  const int n0 = (blk % (NN / 8)) * 8;

  float2* h2 = (float2*)h_lds;
#pragma unroll
  for (int m = 0; m < 8; ++m) h2[m * 64 + jp] = make_float2(0.f, 0.f);

  float c[16];
#pragma unroll
  for (int i = 0; i < 16; ++i) c[i] = 0.f;

  float bq[8];
#pragma unroll
  for (int gi = 0; gi < 8; ++gi) bq[gi] = bias[(gi >> 1) * 128 + 2 * jp + (gi & 1)];

  const float4* __restrict__ wq = (const float4*)Wq_hh;
  const float4* __restrict__ wiq = (const float4*)Wq_ih;
  const float4* __restrict__ x4 = (const float4*)x;
  float4* x4l = (float4*)x_lds;
  const float4* h4 = (const float4*)h_lds;
  const float4* x4r = (const float4*)x_lds;

  const int m0 = jp >> 3, f40 = jp & 7;
  // prologue: stage x(t=0)
  float4 xv = x4[(((size_t)b * TT + 0) * NN + n0 + m0) * 8 + f40];
  x4l[m0 * 8 + f40] = xv;
  __syncthreads();

  for (int t = 0; t < TT; ++t) {
    float4 xnext;
    if (t < TT - 1) xnext = x4[(((size_t)b * TT + t + 1) * NN + n0 + m0) * 8 + f40];

    float a[8][8];  // [m][gi]
#pragma unroll
    for (int m = 0; m < 8; ++m)
#pragma unroll
      for (int gi = 0; gi < 8; ++gi) a[m][gi] = bq[gi];

    // recurrence: h(t-1) @ W_hh^T
    for (int k4 = 0; k4 < 32; ++k4) {
      float4 w[8];
#pragma unroll
      for (int gi = 0; gi < 8; ++gi) w[gi] = wq[(k4 * 8 + gi) * 64 + jp];
#pragma unroll
      for (int m = 0; m < 8; ++m) {
        float4 hv = h4[m * 32 + k4];
#pragma unroll
        for (int gi = 0; gi < 8; ++gi)
          a[m][gi] += hv.x * w[gi].x + hv.y * w[gi].y + hv.z * w[gi].z + hv.w * w[gi].w;
      }
    }

    // input projection: x(t) @ W_ih^T
#pragma unroll
    for (int f4 = 0; f4 < 8; ++f4) {
      float4 w[8];
#pragma unroll
      for (int gi = 0; gi < 8; ++gi) w[gi] = wiq[(f4 * 8 + gi) * 64 + jp];
#pragma unroll
      for (int m = 0; m < 8; ++m) {
        float4 xr = x4r[m * 8 + f4];
#pragma unroll
        for (int gi = 0; gi < 8; ++gi)
          a[m][gi] += xr.x * w[gi].x + xr.y * w[gi].y + xr.z * w[gi].z + xr.w * w[gi].w;
      }
    }

    __syncthreads();  // all h/x reads done before overwrite

    // gates (i,f,g,o) + state update
#pragma unroll
    for (int m = 0; m < 8; ++m) {
      float hv2[2];
#pragma unroll
      for (int jj = 0; jj < 2; ++jj) {
        float iv = fsig(a[m][0 + jj]);
        float fv = fsig(a[m][2 + jj]);
        float gv = ftanh(a[m][4 + jj]);
        float ov = fsig(a[m][6 + jj]);
        float cc = fv * c[m * 2 + jj] + iv * gv;
        c[m * 2 + jj] = cc;
        hv2[jj] = ov * ftanh(cc);
      }
      h2[m * 64 + jp] = make_float2(hv2[0], hv2[1]);
      if (t == TT - 1) {
        float2* ho2 = (float2*)h_out;
        ho2[((size_t)(b * NN + n0 + m)) * 64 + jp] = make_float2(hv2[0], hv2[1]);
      }
    }
    if (t < TT - 1) x4l[m0 * 8 + f40] = xnext;
    __syncthreads();  // h/x visible for next step
  }
}

// ---------- GCN ----------
__global__ void deg_kernel(const int* __restrict__ ei, float* __restrict__ deg) {
  int e = blockIdx.x * 256 + threadIdx.x;
  if (e < EE) atomicAdd(&deg[ei[EE + e]], 1.0f);  // dst row
}

__global__ void dinv_kernel(const float* __restrict__ deg, float* __restrict__ dinv) {
  int n = blockIdx.x * 256 + threadIdx.x;
  if (n < NN) dinv[n] = 1.0f / sqrtf(deg[n]);  // deg >= 1 (self loop)
}

// xw[b,n,g] = sum_k h[b,n,k] * gcn_W[g,k]  ; 8 rows per block
__global__ __launch_bounds__(128) void xw_kernel(const float* __restrict__ h,
                                                 const float* __restrict__ gcn_WT,
                                                 float* __restrict__ xw) {
  const int r0 = blockIdx.x * 8;
  const int g = threadIdx.x;
  __shared__ float hs[8][HH];
  for (int m = 0; m < 8; ++m) hs[m][g] = h[(size_t)(r0 + m) * HH + g];
  __syncthreads();
  float acc[8] = {0, 0, 0, 0, 0, 0, 0, 0};
#pragma unroll 4
  for (int k = 0; k < HH; ++k) {
    float w = gcn_WT[k * HH + g];
#pragma unroll
    for (int m = 0; m < 8; ++m) acc[m] += hs[m][k] * w;
  }
  for (int m = 0; m < 8; ++m) xw[(size_t)(r0 + m) * HH + g] = acc[m];
}

// scatter: agg[b,dst,:] += xw[b,src,:] * norm(e); thread = (edge, channel)
__global__ void scatter_kernel(const int* __restrict__ ei, const float* __restrict__ xw,
                               const float* __restrict__ dinv, float* __restrict__ agg) {
  int gid = blockIdx.x * 256 + threadIdx.x;
  int e = gid >> 7;
  int jj = gid & 127;
  if (e >= EE) return;
  int s = ei[e];
  int d = ei[EE + e];
  float nrm = dinv[s] * dinv[d];
#pragma unroll
  for (int b = 0; b < NB; ++b) {
    float v = xw[((size_t)b * NN + s) * HH + jj] * nrm;
    atomicAdd(&agg[((size_t)b * NN + d) * HH + jj], v);
  }
}

// final: add self-loop + bias, relu, two dot heads. one wave per row.
__global__ __launch_bounds__(256) void final_kernel(
    const float* __restrict__ agg, const float* __restrict__ xw, const float* __restrict__ dinv,
    const float* __restrict__ gcn_b, const float* __restrict__ fcw_c, const float* __restrict__ fcb_c,
    const float* __restrict__ fcw_i, const float* __restrict__ fcb_i, float* __restrict__ out) {
  int row = blockIdx.x * 4 + (threadIdx.x >> 6);
  int lane = threadIdx.x & 63;
  int n = row % NN;
  float sn = dinv[n] * dinv[n];
  float sc = 0.0f, si = 0.0f;
  for (int jj = lane; jj < HH; jj += 64) {
    float v = agg[(size_t)row * HH + jj] + xw[(size_t)row * HH + jj] * sn + gcn_b[jj];
    v = fmaxf(v, 0.0f);
    sc += v * fcw_c[jj];
    si += v * fcw_i[jj];
  }
#pragma unroll
  for (int off = 32; off > 0; off >>= 1) {
    sc += __shfl_down(sc, off);
    si += __shfl_down(si, off);
  }
  if (lane == 0) {
    out[row] = sc + fcb_c[0];
    out[NB * NN + row] = si + fcb_i[0];
  }
}

extern "C" void kernel_launch(void* const* d_in, const int* in_sizes, int n_in,
                              void* d_out, int out_size, void* d_ws, size_t ws_size,
                              hipStream_t stream) {
  const float* x     = (const float*)d_in[0];
  const int*   ei    = (const int*)d_in[1];
  const float* W_ih  = (const float*)d_in[2];
  const float* W_hh  = (const float*)d_in[3];
  const float* b_ih  = (const float*)d_in[4];
  const float* b_hh  = (const float*)d_in[5];
  const float* gcn_W = (const float*)d_in[6];
  const float* gcn_b = (const float*)d_in[7];
  const float* fcw_c = (const float*)d_in[8];
  const float* fcb_c = (const float*)d_in[9];
  const float* fcw_i = (const float*)d_in[10];
  const float* fcb_i = (const float*)d_in[11];
  float* out = (float*)d_out;

  float* ws     = (float*)d_ws;
  float* Wq_hh  = ws;                    // 65536
  float* Wq_ih  = Wq_hh + 65536;         // 16384
  float* gcn_WT = Wq_ih + 16384;         // 16384
  float* bias   = gcn_WT + 16384;        // 512
  float* deg    = bias + 512;            // 4000
  float* dinv   = deg + 4000;            // 4000
  float* h_all  = dinv + 4000;           // 4,096,000
  float* xw     = h_all + 4096000;       // 4,096,000
  float* agg    = xw + 4096000;          // 4,096,000

  setup_kernel<<<402, 256, 0, stream>>>(W_ih, W_hh, b_ih, b_hh, gcn_W,
                                        Wq_hh, Wq_ih, gcn_WT, bias, deg);
  hipMemsetAsync(agg, 0, (size_t)4096000 * sizeof(float), stream);
  lstm_kernel<<<(NB * NN) / 8, 64, 0, stream>>>(x, Wq_ih, Wq_hh, bias, h_all);
  deg_kernel<<<EE / 256, 256, 0, stream>>>(ei, deg);
  dinv_kernel<<<(NN + 255) / 256, 256, 0, stream>>>(deg, dinv);
  xw_kernel<<<(NB * NN) / 8, 128, 0, stream>>>(h_all, gcn_WT, xw);
  scatter_kernel<<<(EE * 128) / 256, 256, 0, stream>>>(ei, xw, dinv, agg);
  final_kernel<<<(NB * NN) / 4, 256, 0, stream>>>(agg, xw, dinv, gcn_b, fcw_c, fcb_c,
                                                  fcw_i, fcb_i, out);
}

// Round 3
// 5752.010 us; speedup vs baseline: 2.1580x; 2.1580x over previous
//
#include <hip/hip_runtime.h>

#define NB 8
#define TT 24
#define NN 4000
#define FF 32
#define HH 128
#define EE 64000

__device__ __forceinline__ float fsig(float x) { return 1.0f / (1.0f + __expf(-x)); }
__device__ __forceinline__ float ftanh(float x) { float e = __expf(2.0f * x); return 1.0f - 2.0f / (e + 1.0f); }

// ---------- setup: pack weights, combine bias, init deg ----------
// Wp_hh packed: Wp[((k4*4+g)*128 + j)*4 + q] = W_hh[(g*128+j)*128 + k4*4+q]
// Wp_ih packed: Wp[((f4*4+g)*128 + j)*4 + q] = W_ih[(g*128+j)*32  + f4*4+q]
__global__ void setup_kernel(const float* __restrict__ W_ih, const float* __restrict__ W_hh,
                             const float* __restrict__ b_ih, const float* __restrict__ b_hh,
                             const float* __restrict__ gcn_W,
                             float* __restrict__ Wp_hh, float* __restrict__ Wp_ih,
                             float* __restrict__ gcn_WT, float* __restrict__ bias,
                             float* __restrict__ deg) {
  int idx = blockIdx.x * 256 + threadIdx.x;
  if (idx < 65536) {
    int q = idx & 3, j = (idx >> 2) & 127, g = (idx >> 9) & 3, k4 = idx >> 11;
    Wp_hh[idx] = W_hh[(g * 128 + j) * 128 + k4 * 4 + q];
  } else if (idx < 65536 + 16384) {
    int i2 = idx - 65536;
    int q = i2 & 3, j = (i2 >> 2) & 127, g = (i2 >> 9) & 3, f4 = i2 >> 11;
    Wp_ih[i2] = W_ih[(g * 128 + j) * 32 + f4 * 4 + q];
  } else if (idx < 65536 + 16384 + 16384) {
    int i2 = idx - 65536 - 16384;
    int g = i2 & 127, k = i2 >> 7;
    gcn_WT[i2] = gcn_W[g * 128 + k];
  } else if (idx < 65536 + 16384 + 16384 + 512) {
    int g = idx - (65536 + 16384 + 16384);
    bias[g] = b_ih[g] + b_hh[g];
  } else if (idx < 65536 + 16384 + 16384 + 512 + NN) {
    int n = idx - (65536 + 16384 + 16384 + 512);
    deg[n] = 1.0f;  // self-loop
  }
}

// ---------- LSTM: 128 threads (2 waves), 8 sequences/block ----------
// thread j owns gate-cols (i,f,g,o) at hidden column j for all 8 seqs:
// 32 accumulators + c[8] + 16 weight regs ~= 80 live VGPRs -> no spill.
__global__ __launch_bounds__(128) void lstm_kernel(
    const float* __restrict__ x,       // [B,T,N,F]
    const float* __restrict__ Wp_ih,   // packed
    const float* __restrict__ Wp_hh,   // packed
    const float* __restrict__ bias,    // [512] combined
    float* __restrict__ h_out)         // [B*N, H]
{
  __shared__ float h_lds[8 * HH];
  __shared__ float x_lds[8 * FF];
  const int j = threadIdx.x;
  const int blk = blockIdx.x;
  const int b = blk / (NN / 8);
  const int n0 = (blk % (NN / 8)) * 8;

#pragma unroll
  for (int m = 0; m < 8; ++m) h_lds[m * HH + j] = 0.0f;

  float c[8];
#pragma unroll
  for (int m = 0; m < 8; ++m) c[m] = 0.0f;
  const float bi = bias[j], bf = bias[128 + j], bg = bias[256 + j], bo = bias[384 + j];

  const float4* __restrict__ wp = (const float4*)Wp_hh;
  const float4* __restrict__ wip = (const float4*)Wp_ih;
  const float4* __restrict__ x4 = (const float4*)x;
  float4* x4l = (float4*)x_lds;
  const float4* h4 = (const float4*)h_lds;   // [m*32 + k4], broadcast reads
  const float4* x4r = (const float4*)x_lds;  // [m*8 + f4],  broadcast reads

  // stage x(t=0): 8 seq x 32 feat = 64 float4, threads 0..63
  if (j < 64) x4l[j] = x4[(((size_t)b * TT + 0) * NN + n0) * 8 + j];
  __syncthreads();

  for (int t = 0; t < TT; ++t) {
    float4 xnext;
    if (j < 64 && t < TT - 1) xnext = x4[(((size_t)b * TT + t + 1) * NN + n0) * 8 + j];

    float ai[8], af[8], ag[8], ao[8];
#pragma unroll
    for (int m = 0; m < 8; ++m) { ai[m] = bi; af[m] = bf; ag[m] = bg; ao[m] = bo; }

    // recurrence: h(t-1) @ W_hh^T
    for (int k4 = 0; k4 < 32; ++k4) {
      float4 wi = wp[(k4 * 4 + 0) * 128 + j];
      float4 wf = wp[(k4 * 4 + 1) * 128 + j];
      float4 wg = wp[(k4 * 4 + 2) * 128 + j];
      float4 wo = wp[(k4 * 4 + 3) * 128 + j];
#pragma unroll
      for (int m = 0; m < 8; ++m) {
        float4 hv = h4[m * 32 + k4];
        ai[m] += hv.x * wi.x + hv.y * wi.y + hv.z * wi.z + hv.w * wi.w;
        af[m] += hv.x * wf.x + hv.y * wf.y + hv.z * wf.z + hv.w * wf.w;
        ag[m] += hv.x * wg.x + hv.y * wg.y + hv.z * wg.z + hv.w * wg.w;
        ao[m] += hv.x * wo.x + hv.y * wo.y + hv.z * wo.z + hv.w * wo.w;
      }
    }

    // input projection: x(t) @ W_ih^T
#pragma unroll
    for (int f4 = 0; f4 < 8; ++f4) {
      float4 wi = wip[(f4 * 4 + 0) * 128 + j];
      float4 wf = wip[(f4 * 4 + 1) * 128 + j];
      float4 wg = wip[(f4 * 4 + 2) * 128 + j];
      float4 wo = wip[(f4 * 4 + 3) * 128 + j];
#pragma unroll
      for (int m = 0; m < 8; ++m) {
        float4 xr = x4r[m * 8 + f4];
        ai[m] += xr.x * wi.x + xr.y * wi.y + xr.z * wi.z + xr.w * wi.w;
        af[m] += xr.x * wf.x + xr.y * wf.y + xr.z * wf.z + xr.w * wf.w;
        ag[m] += xr.x * wg.x + xr.y * wg.y + xr.z * wg.z + xr.w * wg.w;
        ao[m] += xr.x * wo.x + xr.y * wo.y + xr.z * wo.z + xr.w * wo.w;
      }
    }

    __syncthreads();  // all h/x reads done before overwrite

    // gates (PyTorch order i,f,g,o)
#pragma unroll
    for (int m = 0; m < 8; ++m) {
      float iv = fsig(ai[m]);
      float fv = fsig(af[m]);
      float gv = ftanh(ag[m]);
      float ov = fsig(ao[m]);
      float cc = fv * c[m] + iv * gv;
      c[m] = cc;
      float hh = ov * ftanh(cc);
      h_lds[m * HH + j] = hh;
      if (t == TT - 1) h_out[((size_t)(b * NN + n0 + m)) * HH + j] = hh;
    }
    if (j < 64 && t < TT - 1) x4l[j] = xnext;
    __syncthreads();  // h/x visible for next step
  }
}

// ---------- GCN ----------
__global__ void deg_kernel(const int* __restrict__ ei, float* __restrict__ deg) {
  int e = blockIdx.x * 256 + threadIdx.x;
  if (e < EE) atomicAdd(&deg[ei[EE + e]], 1.0f);  // dst row
}

__global__ void dinv_kernel(const float* __restrict__ deg, float* __restrict__ dinv) {
  int n = blockIdx.x * 256 + threadIdx.x;
  if (n < NN) dinv[n] = 1.0f / sqrtf(deg[n]);  // deg >= 1 (self loop)
}

// xw[b,n,g] = sum_k h[b,n,k] * gcn_W[g,k]  ; 8 rows per block
__global__ __launch_bounds__(128) void xw_kernel(const float* __restrict__ h,
                                                 const float* __restrict__ gcn_WT,
                                                 float* __restrict__ xw) {
  const int r0 = blockIdx.x * 8;
  const int g = threadIdx.x;
  __shared__ float hs[8][HH];
  for (int m = 0; m < 8; ++m) hs[m][g] = h[(size_t)(r0 + m) * HH + g];
  __syncthreads();
  float acc[8] = {0, 0, 0, 0, 0, 0, 0, 0};
#pragma unroll 4
  for (int k = 0; k < HH; ++k) {
    float w = gcn_WT[k * HH + g];
#pragma unroll
    for (int m = 0; m < 8; ++m) acc[m] += hs[m][k] * w;
  }
  for (int m = 0; m < 8; ++m) xw[(size_t)(r0 + m) * HH + g] = acc[m];
}

// scatter: agg[b,dst,:] += xw[b,src,:] * norm(e); thread = (edge, channel)
__global__ void scatter_kernel(const int* __restrict__ ei, const float* __restrict__ xw,
                               const float* __restrict__ dinv, float* __restrict__ agg) {
  int gid = blockIdx.x * 256 + threadIdx.x;
  int e = gid >> 7;
  int jj = gid & 127;
  if (e >= EE) return;
  int s = ei[e];
  int d = ei[EE + e];
  float nrm = dinv[s] * dinv[d];
#pragma unroll
  for (int b = 0; b < NB; ++b) {
    float v = xw[((size_t)b * NN + s) * HH + jj] * nrm;
    atomicAdd(&agg[((size_t)b * NN + d) * HH + jj], v);
  }
}

// final: add self-loop + bias, relu, two dot heads. one wave per row.
__global__ __launch_bounds__(256) void final_kernel(
    const float* __restrict__ agg, const float* __restrict__ xw, const float* __restrict__ dinv,
    const float* __restrict__ gcn_b, const float* __restrict__ fcw_c, const float* __restrict__ fcb_c,
    const float* __restrict__ fcw_i, const float* __restrict__ fcb_i, float* __restrict__ out) {
  int row = blockIdx.x * 4 + (threadIdx.x >> 6);
  int lane = threadIdx.x & 63;
  int n = row % NN;
  float sn = dinv[n] * dinv[n];
  float sc = 0.0f, si = 0.0f;
  for (int jj = lane; jj < HH; jj += 64) {
    float v = agg[(size_t)row * HH + jj] + xw[(size_t)row * HH + jj] * sn + gcn_b[jj];
    v = fmaxf(v, 0.0f);
    sc += v * fcw_c[jj];
    si += v * fcw_i[jj];
  }
#pragma unroll
  for (int off = 32; off > 0; off >>= 1) {
    sc += __shfl_down(sc, off);
    si += __shfl_down(si, off);
  }
  if (lane == 0) {
    out[row] = sc + fcb_c[0];
    out[NB * NN + row] = si + fcb_i[0];
  }
}

extern "C" void kernel_launch(void* const* d_in, const int* in_sizes, int n_in,
                              void* d_out, int out_size, void* d_ws, size_t ws_size,
                              hipStream_t stream) {
  const float* x     = (const float*)d_in[0];
  const int*   ei    = (const int*)d_in[1];
  const float* W_ih  = (const float*)d_in[2];
  const float* W_hh  = (const float*)d_in[3];
  const float* b_ih  = (const float*)d_in[4];
  const float* b_hh  = (const float*)d_in[5];
  const float* gcn_W = (const float*)d_in[6];
  const float* gcn_b = (const float*)d_in[7];
  const float* fcw_c = (const float*)d_in[8];
  const float* fcb_c = (const float*)d_in[9];
  const float* fcw_i = (const float*)d_in[10];
  const float* fcb_i = (const float*)d_in[11];
  float* out = (float*)d_out;

  float* ws     = (float*)d_ws;
  float* Wp_hh  = ws;                    // 65536
  float* Wp_ih  = Wp_hh + 65536;         // 16384
  float* gcn_WT = Wp_ih + 16384;         // 16384
  float* bias   = gcn_WT + 16384;        // 512
  float* deg    = bias + 512;            // 4000
  float* dinv   = deg + 4000;            // 4000
  float* h_all  = dinv + 4000;           // 4,096,000
  float* xw     = h_all + 4096000;       // 4,096,000
  float* agg    = xw + 4096000;          // 4,096,000

  setup_kernel<<<402, 256, 0, stream>>>(W_ih, W_hh, b_ih, b_hh, gcn_W,
                                        Wp_hh, Wp_ih, gcn_WT, bias, deg);
  hipMemsetAsync(agg, 0, (size_t)4096000 * sizeof(float), stream);
  lstm_kernel<<<(NB * NN) / 8, 128, 0, stream>>>(x, Wp_ih, Wp_hh, bias, h_all);
  deg_kernel<<<EE / 256, 256, 0, stream>>>(ei, deg);
  dinv_kernel<<<(NN + 255) / 256, 256, 0, stream>>>(deg, dinv);
  xw_kernel<<<(NB * NN) / 8, 128, 0, stream>>>(h_all, gcn_WT, xw);
  scatter_kernel<<<(EE * 128) / 256, 256, 0, stream>>>(ei, xw, dinv, agg);
  final_kernel<<<(NB * NN) / 4, 256, 0, stream>>>(agg, xw, dinv, gcn_b, fcw_c, fcb_c,
                                                  fcw_i, fcb_i, out);
}

// Round 4
// 903.830 us; speedup vs baseline: 13.7334x; 6.3640x over previous
//
#include <hip/hip_runtime.h>

#define NB 8
#define TT 24
#define NN 4000
#define FF 32
#define HH 128
#define EE 64000

typedef float f32x4 __attribute__((ext_vector_type(4)));
typedef short bf16x8 __attribute__((ext_vector_type(8)));
#define MFMA16(a, b, c) __builtin_amdgcn_mfma_f32_16x16x32_bf16(a, b, c, 0, 0, 0)

__device__ __forceinline__ float fsig(float x) { return 1.0f / (1.0f + __expf(-x)); }
__device__ __forceinline__ float ftanh(float x) { float e = __expf(2.0f * x); return 1.0f - 2.0f / (e + 1.0f); }

// round-to-nearest-even fp32 -> bf16; returns bits, sets *hif to the bf16 value as fp32
__device__ __forceinline__ unsigned short rne16(float x, float* hif) {
  unsigned u = __float_as_uint(x);
  unsigned r = (u + 0x7FFFu + ((u >> 16) & 1u)) >> 16;
  *hif = __uint_as_float(r << 16);
  return (unsigned short)r;
}

// ---------- setup: pack weights into B-fragment order (hi/lo split), combine bias, init deg ----------
// Wbh[{hi,lo}] flat p: e=p&7, l=(p>>3)&63, ks=(p>>9)&3, nt=p>>11
//   gate = nt*16 + (l&15), k = ks*32 + (l>>4)*8 + e;  src = W_hh[gate*128 + k]
// Wbi[{hi,lo}] flat p: e=p&7, l=(p>>3)&63, nt=p>>9
//   gate = nt*16 + (l&15), k = (l>>4)*8 + e;          src = W_ih[gate*32 + k]
__global__ void setup_kernel(const float* __restrict__ W_ih, const float* __restrict__ W_hh,
                             const float* __restrict__ b_ih, const float* __restrict__ b_hh,
                             const float* __restrict__ gcn_W,
                             unsigned short* __restrict__ Wbh_hi, unsigned short* __restrict__ Wbh_lo,
                             unsigned short* __restrict__ Wbi_hi, unsigned short* __restrict__ Wbi_lo,
                             float* __restrict__ gcn_WT, float* __restrict__ bias,
                             float* __restrict__ deg) {
  int idx = blockIdx.x * 256 + threadIdx.x;
  if (idx < 65536) {
    int e = idx & 7, l = (idx >> 3) & 63, ks = (idx >> 9) & 3, nt = idx >> 11;
    int gate = nt * 16 + (l & 15);
    int k = ks * 32 + (l >> 4) * 8 + e;
    float wv = W_hh[gate * 128 + k];
    float hif;
    unsigned short hb = rne16(wv, &hif);
    float d;
    unsigned short lb = rne16(wv - hif, &d);
    Wbh_hi[idx] = hb;
    Wbh_lo[idx] = lb;
  } else if (idx < 65536 + 16384) {
    int p = idx - 65536;
    int e = p & 7, l = (p >> 3) & 63, nt = p >> 9;
    int gate = nt * 16 + (l & 15);
    int k = (l >> 4) * 8 + e;
    float wv = W_ih[gate * 32 + k];
    float hif;
    unsigned short hb = rne16(wv, &hif);
    float d;
    unsigned short lb = rne16(wv - hif, &d);
    Wbi_hi[p] = hb;
    Wbi_lo[p] = lb;
  } else if (idx < 65536 + 16384 + 16384) {
    int p = idx - 65536 - 16384;
    int g = p & 127, k = p >> 7;
    gcn_WT[p] = gcn_W[g * 128 + k];
  } else if (idx < 65536 + 16384 + 16384 + 512) {
    int g = idx - (65536 + 16384 + 16384);
    bias[g] = b_ih[g] + b_hh[g];
  } else if (idx < 65536 + 16384 + 16384 + 512 + NN) {
    int n = idx - (65536 + 16384 + 16384 + 512);
    deg[n] = 1.0f;  // self-loop
  }
}

// ---------- LSTM via split-bf16 MFMA: 8 waves, 32 seqs/block ----------
// wave w owns n-tiles {w, 8+w, 16+w, 24+w} (= gates g*128 + [16w,16w+16)) for both M-tiles.
// h exchanged via double-buffered, XOR-swizzled LDS (hi/lo bf16). One barrier per step.
__global__ __launch_bounds__(512) void lstm_kernel(
    const float* __restrict__ x,             // [B,T,N,F]
    const unsigned short* __restrict__ Wbh_hi, const unsigned short* __restrict__ Wbh_lo,
    const unsigned short* __restrict__ Wbi_hi, const unsigned short* __restrict__ Wbi_lo,
    const float* __restrict__ bias,          // [512] combined
    float* __restrict__ h_out)               // [B*N, H] fp32
{
  __shared__ unsigned short hbuf[2][2][32 * 128];  // [buf][hi/lo][seq*128+j] : 32 KB
  const int tid = threadIdx.x;
  const int w = tid >> 6, l = tid & 63;
  const int col = l & 15, kc = l >> 4;
  const int jj = 16 * w + col;  // hidden column owned by this lane
  const int blk = blockIdx.x;
  const int b = blk / (NN / 32);
  const int n0 = (blk % (NN / 32)) * 32;

  // zero h(0) buffer (both splits)
  {
    unsigned short* hb0 = &hbuf[0][0][0];
    for (int i = tid; i < 2 * 32 * 128; i += 512) hb0[i] = 0;
  }

  float bv[4];
#pragma unroll
  for (int g = 0; g < 4; ++g) bv[g] = bias[g * 128 + jj];

  float cst[8];
#pragma unroll
  for (int i = 0; i < 8; ++i) cst[i] = 0.0f;

  __syncthreads();

  for (int t = 0; t < TT; ++t) {
    const char* hr_hi = (const char*)&hbuf[t & 1][0][0];
    const char* hr_lo = (const char*)&hbuf[t & 1][1][0];
    char* hw_hi = (char*)&hbuf[(t + 1) & 1][0][0];
    char* hw_lo = (char*)&hbuf[(t + 1) & 1][1][0];

    // ---- x(t) fragments: load 8 contiguous floats per lane, split to bf16 hi/lo ----
    bf16x8 xh[2], xl[2];
#pragma unroll
    for (int mt = 0; mt < 2; ++mt) {
      const float* xb = x + (((size_t)b * TT + t) * NN + (n0 + mt * 16 + col)) * FF + kc * 8;
      float4 p0 = *(const float4*)xb;
      float4 p1 = *(const float4*)(xb + 4);
      float xf[8] = {p0.x, p0.y, p0.z, p0.w, p1.x, p1.y, p1.z, p1.w};
#pragma unroll
      for (int e = 0; e < 8; ++e) {
        float hif, d;
        xh[mt][e] = (short)rne16(xf[e], &hif);
        xl[mt][e] = (short)rne16(xf[e] - hif, &d);
      }
    }

    // ---- init accumulators with bias ----
    f32x4 acc[2][4];
#pragma unroll
    for (int mt = 0; mt < 2; ++mt)
#pragma unroll
      for (int g = 0; g < 4; ++g) acc[mt][g] = (f32x4){bv[g], bv[g], bv[g], bv[g]};

    // ---- recurrence: h(t-1) @ W_hh^T, split-bf16 (3 MFMA per tile per k-step) ----
#pragma unroll
    for (int ks = 0; ks < 4; ++ks) {
      bf16x8 wh[4], wl[4];
#pragma unroll
      for (int g = 0; g < 4; ++g) {
        int nt = g * 8 + w;
        size_t off = ((size_t)(nt * 4 + ks) * 64 + l) * 8;
        wh[g] = *(const bf16x8*)(Wbh_hi + off);
        wl[g] = *(const bf16x8*)(Wbh_lo + off);
      }
      bf16x8 ah[2], al[2];
#pragma unroll
      for (int mt = 0; mt < 2; ++mt) {
        int seq = mt * 16 + col;
        int off = (seq * 256 + ks * 64 + kc * 16) ^ ((seq & 7) << 4);
        ah[mt] = *(const bf16x8*)(hr_hi + off);
        al[mt] = *(const bf16x8*)(hr_lo + off);
      }
#pragma unroll
      for (int mt = 0; mt < 2; ++mt)
#pragma unroll
        for (int g = 0; g < 4; ++g) {
          acc[mt][g] = MFMA16(ah[mt], wh[g], acc[mt][g]);
          acc[mt][g] = MFMA16(ah[mt], wl[g], acc[mt][g]);
          acc[mt][g] = MFMA16(al[mt], wh[g], acc[mt][g]);
        }
    }

    // ---- input projection: x(t) @ W_ih^T (K=32, one k-step) ----
    {
      bf16x8 wih[4], wil[4];
#pragma unroll
      for (int g = 0; g < 4; ++g) {
        int nt = g * 8 + w;
        size_t off = ((size_t)nt * 64 + l) * 8;
        wih[g] = *(const bf16x8*)(Wbi_hi + off);
        wil[g] = *(const bf16x8*)(Wbi_lo + off);
      }
#pragma unroll
      for (int mt = 0; mt < 2; ++mt)
#pragma unroll
        for (int g = 0; g < 4; ++g) {
          acc[mt][g] = MFMA16(xh[mt], wih[g], acc[mt][g]);
          acc[mt][g] = MFMA16(xh[mt], wil[g], acc[mt][g]);
          acc[mt][g] = MFMA16(xl[mt], wih[g], acc[mt][g]);
        }
    }

    // ---- gates (i,f,g,o) + state update; write split h to other LDS buffer ----
#pragma unroll
    for (int mt = 0; mt < 2; ++mt) {
#pragma unroll
      for (int r = 0; r < 4; ++r) {
        float iv = fsig(acc[mt][0][r]);
        float fv = fsig(acc[mt][1][r]);
        float gv = ftanh(acc[mt][2][r]);
        float ov = fsig(acc[mt][3][r]);
        int ci = mt * 4 + r;
        float cc = fv * cst[ci] + iv * gv;
        cst[ci] = cc;
        float hh = ov * ftanh(cc);
        int seq = mt * 16 + kc * 4 + r;
        float hif, d;
        unsigned short hb = rne16(hh, &hif);
        unsigned short lb = rne16(hh - hif, &d);
        int off = (seq * 256 + jj * 2) ^ ((seq & 7) << 4);
        *(unsigned short*)(hw_hi + off) = hb;
        *(unsigned short*)(hw_lo + off) = lb;
        if (t == TT - 1) h_out[((size_t)(b * NN + n0 + seq)) * HH + jj] = hh;
      }
    }
    __syncthreads();
  }
}

// ---------- GCN ----------
__global__ void deg_kernel(const int* __restrict__ ei, float* __restrict__ deg) {
  int e = blockIdx.x * 256 + threadIdx.x;
  if (e < EE) atomicAdd(&deg[ei[EE + e]], 1.0f);  // dst row
}

__global__ void dinv_kernel(const float* __restrict__ deg, float* __restrict__ dinv) {
  int n = blockIdx.x * 256 + threadIdx.x;
  if (n < NN) dinv[n] = 1.0f / sqrtf(deg[n]);  // deg >= 1 (self loop)
}

// xw[b,n,g] = sum_k h[b,n,k] * gcn_W[g,k]  ; 8 rows per block
__global__ __launch_bounds__(128) void xw_kernel(const float* __restrict__ h,
                                                 const float* __restrict__ gcn_WT,
                                                 float* __restrict__ xw) {
  const int r0 = blockIdx.x * 8;
  const int g = threadIdx.x;
  __shared__ float hs[8][HH];
  for (int m = 0; m < 8; ++m) hs[m][g] = h[(size_t)(r0 + m) * HH + g];
  __syncthreads();
  float acc[8] = {0, 0, 0, 0, 0, 0, 0, 0};
#pragma unroll 4
  for (int k = 0; k < HH; ++k) {
    float w = gcn_WT[k * HH + g];
#pragma unroll
    for (int m = 0; m < 8; ++m) acc[m] += hs[m][k] * w;
  }
  for (int m = 0; m < 8; ++m) xw[(size_t)(r0 + m) * HH + g] = acc[m];
}

// scatter: agg[b,dst,:] += xw[b,src,:] * norm(e); thread = (edge, channel)
__global__ void scatter_kernel(const int* __restrict__ ei, const float* __restrict__ xw,
                               const float* __restrict__ dinv, float* __restrict__ agg) {
  int gid = blockIdx.x * 256 + threadIdx.x;
  int e = gid >> 7;
  int jj = gid & 127;
  if (e >= EE) return;
  int s = ei[e];
  int d = ei[EE + e];
  float nrm = dinv[s] * dinv[d];
#pragma unroll
  for (int b = 0; b < NB; ++b) {
    float v = xw[((size_t)b * NN + s) * HH + jj] * nrm;
    atomicAdd(&agg[((size_t)b * NN + d) * HH + jj], v);
  }
}

// final: add self-loop + bias, relu, two dot heads. one wave per row.
__global__ __launch_bounds__(256) void final_kernel(
    const float* __restrict__ agg, const float* __restrict__ xw, const float* __restrict__ dinv,
    const float* __restrict__ gcn_b, const float* __restrict__ fcw_c, const float* __restrict__ fcb_c,
    const float* __restrict__ fcw_i, const float* __restrict__ fcb_i, float* __restrict__ out) {
  int row = blockIdx.x * 4 + (threadIdx.x >> 6);
  int lane = threadIdx.x & 63;
  int n = row % NN;
  float sn = dinv[n] * dinv[n];
  float sc = 0.0f, si = 0.0f;
  for (int jj = lane; jj < HH; jj += 64) {
    float v = agg[(size_t)row * HH + jj] + xw[(size_t)row * HH + jj] * sn + gcn_b[jj];
    v = fmaxf(v, 0.0f);
    sc += v * fcw_c[jj];
    si += v * fcw_i[jj];
  }
#pragma unroll
  for (int off = 32; off > 0; off >>= 1) {
    sc += __shfl_down(sc, off);
    si += __shfl_down(si, off);
  }
  if (lane == 0) {
    out[row] = sc + fcb_c[0];
    out[NB * NN + row] = si + fcb_i[0];
  }
}

extern "C" void kernel_launch(void* const* d_in, const int* in_sizes, int n_in,
                              void* d_out, int out_size, void* d_ws, size_t ws_size,
                              hipStream_t stream) {
  const float* x     = (const float*)d_in[0];
  const int*   ei    = (const int*)d_in[1];
  const float* W_ih  = (const float*)d_in[2];
  const float* W_hh  = (const float*)d_in[3];
  const float* b_ih  = (const float*)d_in[4];
  const float* b_hh  = (const float*)d_in[5];
  const float* gcn_W = (const float*)d_in[6];
  const float* gcn_b = (const float*)d_in[7];
  const float* fcw_c = (const float*)d_in[8];
  const float* fcb_c = (const float*)d_in[9];
  const float* fcw_i = (const float*)d_in[10];
  const float* fcb_i = (const float*)d_in[11];
  float* out = (float*)d_out;

  char* cur = (char*)d_ws;
  unsigned short* Wbh_hi = (unsigned short*)cur; cur += 65536 * 2;
  unsigned short* Wbh_lo = (unsigned short*)cur; cur += 65536 * 2;
  unsigned short* Wbi_hi = (unsigned short*)cur; cur += 16384 * 2;
  unsigned short* Wbi_lo = (unsigned short*)cur; cur += 16384 * 2;
  float* gcn_WT = (float*)cur; cur += 16384 * 4;
  float* bias   = (float*)cur; cur += 512 * 4;
  float* deg    = (float*)cur; cur += 4000 * 4;
  float* dinv   = (float*)cur; cur += 4000 * 4;
  float* h_all  = (float*)cur; cur += (size_t)4096000 * 4;
  float* xw     = (float*)cur; cur += (size_t)4096000 * 4;
  float* agg    = (float*)cur; cur += (size_t)4096000 * 4;

  setup_kernel<<<402, 256, 0, stream>>>(W_ih, W_hh, b_ih, b_hh, gcn_W,
                                        Wbh_hi, Wbh_lo, Wbi_hi, Wbi_lo,
                                        gcn_WT, bias, deg);
  hipMemsetAsync(agg, 0, (size_t)4096000 * sizeof(float), stream);
  lstm_kernel<<<(NB * NN) / 32, 512, 0, stream>>>(x, Wbh_hi, Wbh_lo, Wbi_hi, Wbi_lo,
                                                  bias, h_all);
  deg_kernel<<<EE / 256, 256, 0, stream>>>(ei, deg);
  dinv_kernel<<<(NN + 255) / 256, 256, 0, stream>>>(deg, dinv);
  xw_kernel<<<(NB * NN) / 8, 128, 0, stream>>>(h_all, gcn_WT, xw);
  scatter_kernel<<<(EE * 128) / 256, 256, 0, stream>>>(ei, xw, dinv, agg);
  final_kernel<<<(NB * NN) / 4, 256, 0, stream>>>(agg, xw, dinv, gcn_b, fcw_c, fcb_c,
                                                  fcw_i, fcb_i, out);
}